// Round 6
// baseline (99.458 us; speedup 1.0000x reference)
//
#include <hip/hip_runtime.h>

// B=8, N=256, D=128, 2D=256.
// out = tour [8,256] (arange) ++ improvement_matrix [8,256,256].

typedef __attribute__((ext_vector_type(8))) short short8;
typedef __attribute__((ext_vector_type(8))) _Float16 half8;
typedef __attribute__((ext_vector_type(4))) float floatx4;

static __device__ __forceinline__ unsigned short f2bf(float f) {
  unsigned int x = __float_as_uint(f);
  x += 0x7fff + ((x >> 16) & 1);   // RNE fp32 -> bf16
  return (unsigned short)(x >> 16);
}

static __device__ __forceinline__ unsigned short f2h(float f) {
  _Float16 h = (_Float16)f;        // RNE fp32 -> fp16
  return __builtin_bit_cast(unsigned short, h);
}

static __device__ __forceinline__ float fast_tanh(float x) {
  float e = __expf(2.0f * fabsf(x));                       // e^{2|x|}
  float t = 1.0f - 2.0f * __builtin_amdgcn_rcpf(e + 1.0f); // in [0,1)
  return copysignf(t, x);
}

// pack 8 fp16 -> 8 OCP e4m3 bytes (via f32, v_cvt_pk_fp8_f32)
static __device__ __forceinline__ long pack_fp8(half8 s) {
  int lo = __builtin_amdgcn_cvt_pk_fp8_f32((float)s[0], (float)s[1], 0, false);
  lo = __builtin_amdgcn_cvt_pk_fp8_f32((float)s[2], (float)s[3], lo, true);
  int hi = __builtin_amdgcn_cvt_pk_fp8_f32((float)s[4], (float)s[5], 0, false);
  hi = __builtin_amdgcn_cvt_pk_fp8_f32((float)s[6], (float)s[7], hi, true);
  return (long)(unsigned)lo | ((long)hi << 32);
}

// async global->LDS DMA, 16B per lane. LDS dest = wave-uniform base + lane*16
// (m104); global src is per-lane. Swizzled layouts are achieved by
// PRE-SWIZZLING the global buffer (m173 pattern), dest stays linear.
static __device__ __forceinline__ void gload_lds16(const void* g, void* l) {
  __builtin_amdgcn_global_load_lds(
      (const __attribute__((address_space(1))) unsigned int*)g,
      (__attribute__((address_space(3))) unsigned int*)l, 16, 0, 0);
}

// ---- k_prep: W1->bf16 T | xcat bf16 (ONLY). ------------------------------
// out-fill + W2F8 moved to k_proj's extra blocks (they don't depend on
// k_prep's outputs and k_proj's GEMM part runs at just 1 block/CU).
__global__ __launch_bounds__(256) void k_prep(
    const float* __restrict__ x, const float* __restrict__ W1,
    unsigned short* __restrict__ W1T, unsigned short* __restrict__ xcat) {
  int e = blockIdx.x * 256 + threadIdx.x;   // grid covers 655360
  if (e < 131072) {
    int n = e >> 8, k = e & 255;            // W1T [512 n][256 k]
    int v = k >> 3;                         // 8-ushort (16B) chunk id 0..31
    int sw = (((v & 16) | ((v ^ (n & 15)) & 15)) << 3) | (k & 7);
    W1T[(n << 8) + sw] = f2bf(W1[((k + (n & 256)) << 8) + (n & 255)]);
  } else {
    int e4 = e - 131072;                    // 524288: xcat [2048 r][256 k]
    int r = e4 >> 8, k = e4 & 255;
    int v = k >> 3;
    int sw = (((v & 16) | ((v ^ (r & 15)) & 15)) << 3) | (k & 7);
    int pos = r & 255;
    int pos2 = (k < 128) ? pos : ((pos + 1) & 255);
    xcat[(r << 8) + sw] = f2bf(x[(((r >> 8) << 8) + pos2) * 128 + (k & 127)]);
  }
}

// ---- k_proj: blocks<256: MFMA GEMM -> PiH | PjH; blocks>=256: fill+W2F8. --
// GEMM [2048 rows x 256 K] @ [K x 512 ch]; staging via global_load_lds
// (sources pre-swizzled by k_prep). PiH LINEAR; PjH chunk-swizzled per row
// (key row&15) so k_main DMAs the jt-tile linearly and reads conflict-even.
// Extra blocks: out-fill (tour + zero matrix) and W2->fp8(x16) paired layout:
// chan n -> q=n>>5, which=(n>>4)&1, l=n&15; k-chunk c=k>>3, c'=(c&16)|((c^l)&15);
// byte = q*8192 + l*512 + c'*16 + which*8 + (k&7). One ds_read_b128 yields
// the 8B K=32 frags of chans nt=2q (lo) and nt=2q+1 (hi).
__global__ __launch_bounds__(256) void k_proj(
    const unsigned short* __restrict__ xcat, const unsigned short* __restrict__ W1T,
    const float* __restrict__ b1, unsigned short* __restrict__ PiH,
    unsigned short* __restrict__ PjH, const float* __restrict__ W2,
    float* __restrict__ out, unsigned char* __restrict__ W2F8) {
  const int tid = threadIdx.x;

  if (blockIdx.x >= 256) {                 // ---- fill / W2F8 blocks ----
    int e = (blockIdx.x - 256) * 256 + tid;   // covers 542720
    if (e < 2048) {
      out[e] = (float)(e & 255);           // improved_tour rows = arange
    } else if (e < 526336) {
      out[e] = 0.f;                        // zero matrix (uncovered tiles)
    } else if (e < 542720) {
      int t = e - 526336;                  // 16384 k-pairs of W2
      int p = t >> 7, n = t & 127;         // p = k/2, n = out channel
      float f0 = W2[(2 * p) * 128 + n] * 16.f;   // x16: e4m3 normal range
      float f1 = W2[(2 * p + 1) * 128 + n] * 16.f;
      int v2 = __builtin_amdgcn_cvt_pk_fp8_f32(f0, f1, 0, false);
      int q = n >> 5, which = (n >> 4) & 1, l = n & 15;
      int c = p >> 2, off = (p & 3) * 2;
      int cs = (c & 16) | ((c ^ l) & 15);
      *(unsigned short*)(W2F8 + q * 8192 + l * 512 + cs * 16 + which * 8 + off) =
          (unsigned short)(v2 & 0xffff);
    }
    return;
  }

  const int mg = blockIdx.x >> 3;       // 0..31 row-tile
  const int ng = blockIdx.x & 7;        // 0..7 channel-tile
  const int wr = tid >> 6, lane = tid & 63, quad = lane >> 4, l15 = lane & 15;

  __shared__ unsigned short As[64 * 256];   // 32KB rows tile (swizzled)
  __shared__ unsigned short Bs[64 * 256];   // 32KB W1T tile (swizzled)

  const unsigned short* Asrc = xcat + mg * 64 * 256;
  const unsigned short* Bsrc = W1T + ng * 64 * 256;
#pragma unroll
  for (int it = 0; it < 8; ++it) {
    const int c = it * 256 + wr * 64 + lane;     // 16B chunk id 0..2047
    gload_lds16(Asrc + c * 8, &As[(it * 256 + wr * 64) * 8]);
    gload_lds16(Bsrc + c * 8, &Bs[(it * 256 + wr * 64) * 8]);
  }
  __syncthreads();   // drains the DMA (compiler emits vmcnt(0) before barrier)

  floatx4 acc[4];
#pragma unroll
  for (int mt = 0; mt < 4; ++mt) acc[mt] = (floatx4)0.f;

  const char* Ab = (const char*)As;
  const char* Bb = (const char*)Bs + wr * 16 * 512;
  const int base_sw = l15 * 512 + ((quad ^ l15) << 4);

#pragma unroll
  for (int ks = 0; ks < 8; ++ks) {
    const int swz = base_sw ^ (ks << 6);
    short8 bfr = *(const short8*)(Bb + swz);
#pragma unroll
    for (int mt = 0; mt < 4; ++mt) {
      short8 afr = *(const short8*)(Ab + mt * 8192 + swz);
      acc[mt] = __builtin_amdgcn_mfma_f32_16x16x32_bf16(afr, bfr, acc[mt], 0, 0, 0);
    }
  }

  const int ch = ng * 64 + wr * 16 + l15;          // 0..511 (wave-uniform side)
  const float bias = (ch < 256) ? b1[ch] : 0.f;
  const bool isPi = (ch < 256);
  unsigned short* dst = isPi ? PiH : PjH;
  const int chan = ch & 255;
  const int ck = chan >> 3, coff = chan & 7;
#pragma unroll
  for (int mt = 0; mt < 4; ++mt)
#pragma unroll
    for (int r = 0; r < 4; ++r) {
      int row = mg * 64 + mt * 16 + quad * 4 + r;  // global row b*256+pos
      int cpos;
      if (isPi) cpos = chan;
      else {
        int cs = (ck & 16) | ((ck ^ (row & 15)) & 15);
        cpos = cs * 8 + coff;
      }
      dst[row * 256 + cpos] = f2h(acc[mt][r] + bias);
    }
}

// ---- k_main: 2 i's per wave (M=64) -> W2/Pj LDS reads amortize 2x. ---------
// R5 diagnosis: k_main is LDS-read-volume bound (~2.1MB/CU: every wave reads
// all 32KB of W2 + 16KB Pj per SINGLE i). Fix: M=64 per wave (i0,i0+1):
// per-i LDS reads 48.5KB -> 24.5KB. acc[2][2][8]=128 regs needs the
// __launch_bounds__(256,2) 256-reg budget (est. peak ~223; R1/R2's failures
// were 128/170-reg budgets vs the same ~200 live set). 2 blocks/CU x 52KB
// LDS; 8 waves/CU. Grid 1152: per b, (b,jt) group g has 4(g+1) blocks =
// 32(g+1) i-slots (2 pads/group; pad masks provably empty -> write zeros,
// race-free vs k_proj's fill). Inner loop: zero global loads; per ks
// 8x ds_read_b128 (4 W2-paired + 2 Pj + 2 Pi), depth-1 double-buffered;
// 32-MFMA bursts under setprio.
__global__ __launch_bounds__(256, 2) void k_main(
    const unsigned short* __restrict__ PiH, const unsigned short* __restrict__ PjH,
    const unsigned char* __restrict__ W2F8, const float* __restrict__ b2,
    const float* __restrict__ W3, const float* __restrict__ b3,
    float* __restrict__ outm) {
  const int tid = threadIdx.x;
  const int wr = tid >> 6;              // wave 0..3
  const int lane = tid & 63, quad = lane >> 4, l15 = lane & 15;

  __shared__ unsigned char W2s[32768];  // paired+swizzled fp8
  __shared__ unsigned char PjS[16384];  // 32 rows x 512B, chunk-swizzled
  __shared__ unsigned char PiS[4096];   // 8 rows x 512B (2 per wave)

  // decode block -> (b, jt, i0)   [block-uniform except wr]
  const int bid = blockIdx.x;
  const int b = bid / 144;
  const int rem = bid - b * 144;
  int jt = 0, basej = 0;
  if (rem >= 4)   { jt = 1; basej = 4;   }
  if (rem >= 12)  { jt = 2; basej = 12;  }
  if (rem >= 24)  { jt = 3; basej = 24;  }
  if (rem >= 40)  { jt = 4; basej = 40;  }
  if (rem >= 60)  { jt = 5; basej = 60;  }
  if (rem >= 84)  { jt = 6; basej = 84;  }
  if (rem >= 112) { jt = 7; basej = 112; }
  const int i0 = (rem - basej) * 8 + wr * 2;   // wave's i-pair (i0, i0+1)

  // stage W2 32KB + Pj tile 16KB + 2 Pi rows per wave (1KB)
  const unsigned char* pjsrc =
      (const unsigned char*)(PjH + ((b << 8) + jt * 32) * 256);
  const unsigned char* pisrc =
      (const unsigned char*)(PiH + ((b << 8) + i0 + (lane >> 5)) * 256) +
      (lane & 31) * 16;
#pragma unroll
  for (int it = 0; it < 8; ++it) {
    const int c = it * 256 + wr * 64 + lane;
    gload_lds16(W2F8 + c * 16, &W2s[(it * 256 + wr * 64) * 16]);
  }
#pragma unroll
  for (int it = 0; it < 4; ++it) {
    const int c = it * 256 + wr * 64 + lane;
    gload_lds16(pjsrc + c * 16, &PjS[(it * 256 + wr * 64) * 16]);
  }
  gload_lds16(pisrc, &PiS[wr * 1024]);   // lanes 0-31 -> row i0, 32-63 -> i0+1
  __syncthreads();

  const char* W2base = (const char*)&W2s[0];
  const char* PjBase = (const char*)&PjS[0];
  const char* PiBase = (const char*)&PiS[0] + wr * 1024 + quad * 16;
  // shared chunk-swizzle base for W2 and Pj ([16 rows x 512B], c = ks*4+quad):
  const int sw16 = l15 * 512 + (((quad ^ l15) & 15) << 4);

  floatx4 acc[2][2][8];                 // [is][mt][nt] = 128 regs
#pragma unroll
  for (int is = 0; is < 2; ++is)
#pragma unroll
    for (int mt = 0; mt < 2; ++mt)
#pragma unroll
      for (int nt = 0; nt < 8; ++nt) acc[is][mt][nt] = (floatx4)0.f;

  union U4 { uint4 v; half8 h; };
  U4 piR[2][2], pjR[2][2];              // [buf][is] / [buf][mt]
  piR[0][0].v = *(const uint4*)(PiBase);
  piR[0][1].v = *(const uint4*)(PiBase + 512);
  pjR[0][0].v = *(const uint4*)(PjBase + sw16);
  pjR[0][1].v = *(const uint4*)(PjBase + 8192 + sw16);   // mt=1: +16 rows

  uint4 bfA[4], bfB[4];
  {
    const char* b0 = W2base + sw16;
#pragma unroll
    for (int q = 0; q < 4; ++q) bfA[q] = *(const uint4*)(b0 + q * 8192);
  }

#pragma unroll
  for (int ks = 0; ks < 8; ++ks) {
    const int cur = ks & 1, nxt = cur ^ 1;
    // (1) issue NEXT iteration's B-frag reads (4x b128, paired chans)
    if (ks < 7) {
      const char* bn = W2base + (sw16 ^ ((ks + 1) << 6));
#pragma unroll
      for (int q = 0; q < 4; ++q)
        ((ks & 1) ? bfA : bfB)[q] = *(const uint4*)(bn + q * 8192);
    }
    // (2) depth-1 LDS prefetch of pi/pj for ks+1
    if (ks < 7) {
      piR[nxt][0].v = *(const uint4*)(PiBase + (ks + 1) * 64);
      piR[nxt][1].v = *(const uint4*)(PiBase + 512 + (ks + 1) * 64);
      const char* pj = PjBase + (sw16 ^ ((ks + 1) << 6));
      pjR[nxt][0].v = *(const uint4*)(pj);
      pjR[nxt][1].v = *(const uint4*)(pj + 8192);
    }
    // (3) build 4 A-frags: relu(Pi[is] + Pj[mt]) -> e4m3
    const half8 s00 = __builtin_elementwise_max(piR[cur][0].h + pjR[cur][0].h,
                                                (half8)(_Float16)0);
    const half8 s01 = __builtin_elementwise_max(piR[cur][0].h + pjR[cur][1].h,
                                                (half8)(_Float16)0);
    const half8 s10 = __builtin_elementwise_max(piR[cur][1].h + pjR[cur][0].h,
                                                (half8)(_Float16)0);
    const half8 s11 = __builtin_elementwise_max(piR[cur][1].h + pjR[cur][1].h,
                                                (half8)(_Float16)0);
    const long a00 = pack_fp8(s00), a01 = pack_fp8(s01);
    const long a10 = pack_fp8(s10), a11 = pack_fp8(s11);
    // (4) 32-MFMA burst; lo/hi 8B of each b128 = chans nt=2q / 2q+1
    const uint4* bc = (ks & 1) ? bfB : bfA;
    __builtin_amdgcn_s_setprio(1);
#pragma unroll
    for (int q = 0; q < 4; ++q) {
      const long blo = (long)bc[q].x | ((long)bc[q].y << 32);
      const long bhi = (long)bc[q].z | ((long)bc[q].w << 32);
      acc[0][0][2 * q]     = __builtin_amdgcn_mfma_f32_16x16x32_fp8_fp8(a00, blo, acc[0][0][2 * q], 0, 0, 0);
      acc[0][1][2 * q]     = __builtin_amdgcn_mfma_f32_16x16x32_fp8_fp8(a01, blo, acc[0][1][2 * q], 0, 0, 0);
      acc[1][0][2 * q]     = __builtin_amdgcn_mfma_f32_16x16x32_fp8_fp8(a10, blo, acc[1][0][2 * q], 0, 0, 0);
      acc[1][1][2 * q]     = __builtin_amdgcn_mfma_f32_16x16x32_fp8_fp8(a11, blo, acc[1][1][2 * q], 0, 0, 0);
      acc[0][0][2 * q + 1] = __builtin_amdgcn_mfma_f32_16x16x32_fp8_fp8(a00, bhi, acc[0][0][2 * q + 1], 0, 0, 0);
      acc[0][1][2 * q + 1] = __builtin_amdgcn_mfma_f32_16x16x32_fp8_fp8(a01, bhi, acc[0][1][2 * q + 1], 0, 0, 0);
      acc[1][0][2 * q + 1] = __builtin_amdgcn_mfma_f32_16x16x32_fp8_fp8(a10, bhi, acc[1][0][2 * q + 1], 0, 0, 0);
      acc[1][1][2 * q + 1] = __builtin_amdgcn_mfma_f32_16x16x32_fp8_fp8(a11, bhi, acc[1][1][2 * q + 1], 0, 0, 0);
    }
    __builtin_amdgcn_s_setprio(0);
  }

  // epilogue: score[j] = tanh(sum_n W3[n]*relu(C[j,n]/16 + b2[n]) + b3)
  const float b3v = b3[0];
  const float s16 = 0.0625f;               // undo W2 x16 scale
#pragma unroll
  for (int is = 0; is < 2; ++is) {
    const int i = i0 + is;
    float* orow = outm + ((b << 8) + i) * 256 + jt * 32;
#pragma unroll
    for (int mt = 0; mt < 2; ++mt) {
      float p0 = 0, p1 = 0, p2 = 0, p3 = 0;
#pragma unroll
      for (int nt = 0; nt < 8; ++nt) {
        float w3v = W3[nt * 16 + l15];
        float b2v = b2[nt * 16 + l15];
        floatx4 a = acc[is][mt][nt];
        p0 += fmaxf(fmaf(a[0], s16, b2v), 0.f) * w3v;
        p1 += fmaxf(fmaf(a[1], s16, b2v), 0.f) * w3v;
        p2 += fmaxf(fmaf(a[2], s16, b2v), 0.f) * w3v;
        p3 += fmaxf(fmaf(a[3], s16, b2v), 0.f) * w3v;
      }
#pragma unroll
      for (int m = 8; m >= 1; m >>= 1) {   // reduce over the 16 n-cols per quad
        p0 += __shfl_xor(p0, m, 16);
        p1 += __shfl_xor(p1, m, 16);
        p2 += __shfl_xor(p2, m, 16);
        p3 += __shfl_xor(p3, m, 16);
      }
      if (l15 == 0) {
        const int jl = jt * 32 + mt * 16 + quad * 4;   // global j of reg 0
        float ps[4] = {p0, p1, p2, p3};
#pragma unroll
        for (int r = 0; r < 4; ++r) {
          int j = jl + r;
          float sc = fast_tanh(ps[r] + b3v);
          bool valid = (j >= i + 2) && (j - i != 255);
          orow[mt * 16 + quad * 4 + r] = valid ? sc : 0.f;
        }
      }
    }
  }
}

extern "C" void kernel_launch(void* const* d_in, const int* in_sizes, int n_in,
                              void* d_out, int out_size, void* d_ws, size_t ws_size,
                              hipStream_t stream) {
  const float* x  = (const float*)d_in[0];   // [8,256,128]
  const float* W1 = (const float*)d_in[1];   // [512,256]
  const float* b1 = (const float*)d_in[2];   // [256]
  const float* W2 = (const float*)d_in[3];   // [256,128]
  const float* b2 = (const float*)d_in[4];   // [128]
  const float* W3 = (const float*)d_in[5];   // [128]
  const float* b3 = (const float*)d_in[6];   // [1]
  float* out = (float*)d_out;

  // ws (ushort units): PiH 524288 | PjH 524288 | W1T 131072 | xcat 524288 | W2F8 32KB
  unsigned short* PiH  = (unsigned short*)d_ws;
  unsigned short* PjH  = PiH + 524288;
  unsigned short* W1T  = PjH + 524288;
  unsigned short* xcat = W1T + 131072;
  unsigned char*  W2F8 = (unsigned char*)(xcat + 524288);

  k_prep<<<2560, 256, 0, stream>>>(x, W1, W1T, xcat);
  k_proj<<<2376, 256, 0, stream>>>(xcat, W1T, b1, PiH, PjH, W2, out, W2F8);
  k_main<<<1152, 256, 0, stream>>>(PiH, PjH, W2F8, b2, W3, b3, out + 2048);
}

// Round 7
// 97.269 us; speedup vs baseline: 1.0225x; 1.0225x over previous
//
#include <hip/hip_runtime.h>

// B=8, N=256, D=128, 2D=256.
// out = tour [8,256] (arange) ++ improvement_matrix [8,256,256].

typedef __attribute__((ext_vector_type(8))) short short8;
typedef __attribute__((ext_vector_type(8))) _Float16 half8;
typedef __attribute__((ext_vector_type(4))) float floatx4;

static __device__ __forceinline__ unsigned short f2bf(float f) {
  unsigned int x = __float_as_uint(f);
  x += 0x7fff + ((x >> 16) & 1);   // RNE fp32 -> bf16
  return (unsigned short)(x >> 16);
}

static __device__ __forceinline__ unsigned short f2h(float f) {
  _Float16 h = (_Float16)f;        // RNE fp32 -> fp16
  return __builtin_bit_cast(unsigned short, h);
}

static __device__ __forceinline__ float fast_tanh(float x) {
  float e = __expf(2.0f * fabsf(x));                       // e^{2|x|}
  float t = 1.0f - 2.0f * __builtin_amdgcn_rcpf(e + 1.0f); // in [0,1)
  return copysignf(t, x);
}

// pack 8 fp16 -> 8 OCP e4m3 bytes (via f32, v_cvt_pk_fp8_f32)
static __device__ __forceinline__ long pack_fp8(half8 s) {
  int lo = __builtin_amdgcn_cvt_pk_fp8_f32((float)s[0], (float)s[1], 0, false);
  lo = __builtin_amdgcn_cvt_pk_fp8_f32((float)s[2], (float)s[3], lo, true);
  int hi = __builtin_amdgcn_cvt_pk_fp8_f32((float)s[4], (float)s[5], 0, false);
  hi = __builtin_amdgcn_cvt_pk_fp8_f32((float)s[6], (float)s[7], hi, true);
  return (long)(unsigned)lo | ((long)hi << 32);
}

// async global->LDS DMA, 16B per lane. LDS dest = wave-uniform base + lane*16
// (m104); global src is per-lane. Swizzled layouts are achieved by
// PRE-SWIZZLING the global buffer (m173 pattern), dest stays linear.
static __device__ __forceinline__ void gload_lds16(const void* g, void* l) {
  __builtin_amdgcn_global_load_lds(
      (const __attribute__((address_space(1))) unsigned int*)g,
      (__attribute__((address_space(3))) unsigned int*)l, 16, 0, 0);
}

// ---- k_prep: tour | zero matrix | W2->fp8 paired | W1->bf16 T | xcat bf16 --
// W2F8 layout (paired for b128 B-frag reads): channel n -> np=n>>4,
// q=np>>1, which=np&1, l=n&15; k-chunk c=k>>3 swizzled c'=(c&16)|((c^l)&15).
// byte = q*8192 + l*512 + c'*16 + which*8 + (k&7). One ds_read_b128 then
// yields the 8B K=32 frags of BOTH chans nt=2q (lo) and nt=2q+1 (hi).
__global__ __launch_bounds__(256) void k_prep(
    const float* __restrict__ x, const float* __restrict__ W1,
    const float* __restrict__ W2, float* __restrict__ out,
    unsigned char* __restrict__ W2F8, unsigned short* __restrict__ W1T,
    unsigned short* __restrict__ xcat) {
  int e = blockIdx.x * 256 + threadIdx.x;   // grid covers 1198080
  if (e < 2048) {
    out[e] = (float)(e & 255);              // improved_tour rows = arange
  } else if (e < 526336) {
    out[e] = 0.f;                           // zero matrix (uncovered tiles)
  } else if (e < 542720) {
    int t = e - 526336;                     // 16384 k-pairs of W2
    int p = t >> 7, n = t & 127;            // p = k/2, n = out channel
    float f0 = W2[(2 * p) * 128 + n] * 16.f;       // x16: into e4m3 normal range
    float f1 = W2[(2 * p + 1) * 128 + n] * 16.f;
    int v2 = __builtin_amdgcn_cvt_pk_fp8_f32(f0, f1, 0, false);
    int q = n >> 5, which = (n >> 4) & 1, l = n & 15;
    int c = p >> 2, off = (p & 3) * 2;      // k-chunk = k>>3 = p>>2
    int cs = (c & 16) | ((c ^ l) & 15);
    *(unsigned short*)(W2F8 + q * 8192 + l * 512 + cs * 16 + which * 8 + off) =
        (unsigned short)(v2 & 0xffff);
  } else if (e < 673792) {
    int e3 = e - 542720;                    // 131072: W1T [512 n][256 k]
    int n = e3 >> 8, k = e3 & 255;
    int v = k >> 3;                         // 8-ushort (16B) chunk id 0..31
    int sw = (((v & 16) | ((v ^ (n & 15)) & 15)) << 3) | (k & 7);
    W1T[(n << 8) + sw] = f2bf(W1[((k + (n & 256)) << 8) + (n & 255)]);
  } else {
    int e4 = e - 673792;                    // 524288: xcat [2048 r][256 k]
    int r = e4 >> 8, k = e4 & 255;
    int v = k >> 3;
    int sw = (((v & 16) | ((v ^ (r & 15)) & 15)) << 3) | (k & 7);
    int pos = r & 255;
    int pos2 = (k < 128) ? pos : ((pos + 1) & 255);
    xcat[(r << 8) + sw] = f2bf(x[(((r >> 8) << 8) + pos2) * 128 + (k & 127)]);
  }
}

// ---- k_proj: MFMA GEMM  [2048 rows x 256 K] @ [K x 512 ch] -> PiH | PjH ----
// PiH stays LINEAR (k_main broadcasts rows). PjH is written CHUNK-SWIZZLED
// per row (key = row&15) so k_main can DMA the 32-row jt tile linearly into
// LDS and ds_read conflict-even: chunk c=chan>>3 -> c'=(c&16)|((c^(row&15))&15).
__global__ __launch_bounds__(256) void k_proj(
    const unsigned short* __restrict__ xcat, const unsigned short* __restrict__ W1T,
    const float* __restrict__ b1, unsigned short* __restrict__ PiH,
    unsigned short* __restrict__ PjH) {
  const int mg = blockIdx.x >> 3;       // 0..31 row-tile
  const int ng = blockIdx.x & 7;        // 0..7 channel-tile
  const int tid = threadIdx.x;
  const int wr = tid >> 6, lane = tid & 63, quad = lane >> 4, l15 = lane & 15;

  __shared__ unsigned short As[64 * 256];   // 32KB rows tile (swizzled)
  __shared__ unsigned short Bs[64 * 256];   // 32KB W1T tile (swizzled)

  const unsigned short* Asrc = xcat + mg * 64 * 256;
  const unsigned short* Bsrc = W1T + ng * 64 * 256;
#pragma unroll
  for (int it = 0; it < 8; ++it) {
    const int c = it * 256 + wr * 64 + lane;     // 16B chunk id 0..2047
    gload_lds16(Asrc + c * 8, &As[(it * 256 + wr * 64) * 8]);
    gload_lds16(Bsrc + c * 8, &Bs[(it * 256 + wr * 64) * 8]);
  }
  __syncthreads();   // drains the DMA (compiler emits vmcnt(0) before barrier)

  floatx4 acc[4];
#pragma unroll
  for (int mt = 0; mt < 4; ++mt) acc[mt] = (floatx4)0.f;

  const char* Ab = (const char*)As;
  const char* Bb = (const char*)Bs + wr * 16 * 512;
  const int base_sw = l15 * 512 + ((quad ^ l15) << 4);

#pragma unroll
  for (int ks = 0; ks < 8; ++ks) {
    const int swz = base_sw ^ (ks << 6);
    short8 bfr = *(const short8*)(Bb + swz);
#pragma unroll
    for (int mt = 0; mt < 4; ++mt) {
      short8 afr = *(const short8*)(Ab + mt * 8192 + swz);
      acc[mt] = __builtin_amdgcn_mfma_f32_16x16x32_bf16(afr, bfr, acc[mt], 0, 0, 0);
    }
  }

  const int ch = ng * 64 + wr * 16 + l15;          // 0..511 (wave-uniform side)
  const float bias = (ch < 256) ? b1[ch] : 0.f;
  const bool isPi = (ch < 256);
  unsigned short* dst = isPi ? PiH : PjH;
  const int chan = ch & 255;
  const int ck = chan >> 3, coff = chan & 7;
#pragma unroll
  for (int mt = 0; mt < 4; ++mt)
#pragma unroll
    for (int r = 0; r < 4; ++r) {
      int row = mg * 64 + mt * 16 + quad * 4 + r;  // global row b*256+pos
      int cpos;
      if (isPi) cpos = chan;
      else {
        int cs = (ck & 16) | ((ck ^ (row & 15)) & 15);
        cpos = cs * 8 + coff;
      }
      dst[row * 256 + cpos] = f2h(acc[mt][r] + bias);
    }
}

// ---- k_main: R5 structure + BUILD-AHEAD software pipeline. -----------------
// R6 falsified the LDS-volume theory (halving volume regressed). Remaining
// stall: R5's per-ks serial chain build A(ks) -> burst(ks) (~80cy VALU then
// ~78cy dependent MFMA; both pipes ~50% idle at 3 waves/SIMD). Fix: at iter
// ks, build A(ks+1) BEFORE issuing burst(ks) (whose A-frags were built one
// iteration ago). The MFMA burst no longer depends on its immediately-
// preceding VALU -> scheduler can overlap burst(ks) with build(ks+1).
// pi/pj prefetch moves to depth-2 (ring: write piR[ks&1] for ks+2, read
// piR[(ks+1)&1] -- disjoint parities; full unroll keeps all indices static,
// no rule-#20 scratch hazard). Everything else is R5 verbatim (97.0us best).
__global__ __launch_bounds__(256, 3) void k_main(
    const unsigned short* __restrict__ PiH, const unsigned short* __restrict__ PjH,
    const unsigned char* __restrict__ W2F8, const float* __restrict__ b2,
    const float* __restrict__ W3, const float* __restrict__ b3,
    float* __restrict__ outm) {
  const int tid = threadIdx.x;
  const int wr = tid >> 6;              // wave 0..3
  const int lane = tid & 63, quad = lane >> 4, l15 = lane & 15;

  __shared__ unsigned char W2s[32768];  // paired+swizzled fp8
  __shared__ unsigned char PjS[16384];  // 32 rows x 512B, chunk-swizzled
  __shared__ unsigned char PiS[4096];   // 4 waves x 1024B (row duplicated)

  // decode block -> (b, jt, i-base)   [block-uniform except wr]
  const int bid = blockIdx.x;
  const int b = bid / 288;
  const int rem = bid - b * 288;
  int jt = 0, basej = 0;
  if (rem >= 8)   { jt = 1; basej = 8;   }
  if (rem >= 24)  { jt = 2; basej = 24;  }
  if (rem >= 48)  { jt = 3; basej = 48;  }
  if (rem >= 80)  { jt = 4; basej = 80;  }
  if (rem >= 120) { jt = 5; basej = 120; }
  if (rem >= 168) { jt = 6; basej = 168; }
  if (rem >= 224) { jt = 7; basej = 224; }
  const int i = (rem - basej) * 4 + wr;      // 0 .. (jt+1)*32-1 (2 pads/group)

  // stage W2 32KB (2048 chunks) + Pj tile 16KB (1024 chunks) + Pi row/wave
  const unsigned char* pjsrc =
      (const unsigned char*)(PjH + ((b << 8) + jt * 32) * 256);
  const unsigned char* pisrc =
      (const unsigned char*)(PiH + ((b << 8) + i) * 256);
#pragma unroll
  for (int it = 0; it < 8; ++it) {
    const int c = it * 256 + wr * 64 + lane;
    gload_lds16(W2F8 + c * 16, &W2s[(it * 256 + wr * 64) * 16]);
  }
#pragma unroll
  for (int it = 0; it < 4; ++it) {
    const int c = it * 256 + wr * 64 + lane;
    gload_lds16(pjsrc + c * 16, &PjS[(it * 256 + wr * 64) * 16]);
  }
  gload_lds16(pisrc + (lane & 31) * 16, &PiS[wr * 1024]);  // dup in hi 512B
  __syncthreads();

  const char* W2base = (const char*)&W2s[0];
  const char* PjBase = (const char*)&PjS[0];
  const char* PiBase = (const char*)&PiS[0] + wr * 1024 + quad * 16;
  // shared chunk-swizzle base for W2 and Pj ([16 rows x 512B], c = ks*4+quad):
  const int sw16 = l15 * 512 + (((quad ^ l15) & 15) << 4);

  floatx4 acc[2][8];
#pragma unroll
  for (int mt = 0; mt < 2; ++mt)
#pragma unroll
    for (int nt = 0; nt < 8; ++nt) acc[mt][nt] = (floatx4)0.f;

  union U4 { uint4 v; half8 h; };
  U4 piR[2], pjR[2][2];                 // depth-2 ring, parity-indexed
  piR[0].v = *(const uint4*)(PiBase);
  pjR[0][0].v = *(const uint4*)(PjBase + sw16);
  pjR[0][1].v = *(const uint4*)(PjBase + 8192 + sw16);   // mt=1: +16 rows
  piR[1].v = *(const uint4*)(PiBase + 64);               // ks=1 operands
  {
    const char* pj = PjBase + (sw16 ^ 64);
    pjR[1][0].v = *(const uint4*)(pj);
    pjR[1][1].v = *(const uint4*)(pj + 8192);
  }

  uint4 bfA[4], bfB[4];
  {
    const char* b0 = W2base + sw16;
#pragma unroll
    for (int q = 0; q < 4; ++q) bfA[q] = *(const uint4*)(b0 + q * 8192);
  }

  // build A(0) in the prologue; loop builds A(ks+1) ahead of burst(ks)
  long aC0, aC1;
  {
    const half8 s0 = __builtin_elementwise_max(piR[0].h + pjR[0][0].h,
                                               (half8)(_Float16)0);
    const half8 s1 = __builtin_elementwise_max(piR[0].h + pjR[0][1].h,
                                               (half8)(_Float16)0);
    aC0 = pack_fp8(s0);
    aC1 = pack_fp8(s1);
  }

#pragma unroll
  for (int ks = 0; ks < 8; ++ks) {
    // (1) issue NEXT iteration's B-frag reads (4x b128, paired chans)
    if (ks < 7) {
      const char* bn = W2base + (sw16 ^ ((ks + 1) << 6));
#pragma unroll
      for (int q = 0; q < 4; ++q)
        ((ks & 1) ? bfA : bfB)[q] = *(const uint4*)(bn + q * 8192);
    }
    // (2) depth-2 LDS prefetch of pi/pj for ks+2 (into parity slot ks&1)
    if (ks < 6) {
      piR[ks & 1].v = *(const uint4*)(PiBase + (ks + 2) * 64);
      const char* pj = PjBase + (sw16 ^ ((ks + 2) << 6));
      pjR[ks & 1][0].v = *(const uint4*)(pj);
      pjR[ks & 1][1].v = *(const uint4*)(pj + 8192);
    }
    // (3) BUILD-AHEAD: A(ks+1) from piR[(ks+1)&1] (loaded >=1 iter ago)
    long aN0 = 0, aN1 = 0;
    if (ks < 7) {
      const half8 s0 = __builtin_elementwise_max(
          piR[(ks + 1) & 1].h + pjR[(ks + 1) & 1][0].h, (half8)(_Float16)0);
      const half8 s1 = __builtin_elementwise_max(
          piR[(ks + 1) & 1].h + pjR[(ks + 1) & 1][1].h, (half8)(_Float16)0);
      aN0 = pack_fp8(s0);
      aN1 = pack_fp8(s1);
    }
    // (4) MFMA burst ks with A built LAST iteration (no dep on step 3)
    const uint4* bc = (ks & 1) ? bfB : bfA;
    __builtin_amdgcn_s_setprio(1);
#pragma unroll
    for (int q = 0; q < 4; ++q) {
      const long blo = (long)bc[q].x | ((long)bc[q].y << 32);
      const long bhi = (long)bc[q].z | ((long)bc[q].w << 32);
      acc[0][2 * q]     = __builtin_amdgcn_mfma_f32_16x16x32_fp8_fp8(aC0, blo, acc[0][2 * q], 0, 0, 0);
      acc[1][2 * q]     = __builtin_amdgcn_mfma_f32_16x16x32_fp8_fp8(aC1, blo, acc[1][2 * q], 0, 0, 0);
      acc[0][2 * q + 1] = __builtin_amdgcn_mfma_f32_16x16x32_fp8_fp8(aC0, bhi, acc[0][2 * q + 1], 0, 0, 0);
      acc[1][2 * q + 1] = __builtin_amdgcn_mfma_f32_16x16x32_fp8_fp8(aC1, bhi, acc[1][2 * q + 1], 0, 0, 0);
    }
    __builtin_amdgcn_s_setprio(0);
    if (ks < 7) { aC0 = aN0; aC1 = aN1; }
  }

  // epilogue: score[j] = tanh(sum_n W3[n]*relu(C[j,n]/16 + b2[n]) + b3)
  float* orow = outm + ((b << 8) + i) * 256 + jt * 32;
  const float b3v = b3[0];
  const float s16 = 0.0625f;               // undo W2 x16 scale
#pragma unroll
  for (int mt = 0; mt < 2; ++mt) {
    float p0 = 0, p1 = 0, p2 = 0, p3 = 0;
#pragma unroll
    for (int nt = 0; nt < 8; ++nt) {
      float w3v = W3[nt * 16 + l15];
      float b2v = b2[nt * 16 + l15];
      floatx4 a = acc[mt][nt];
      p0 += fmaxf(fmaf(a[0], s16, b2v), 0.f) * w3v;
      p1 += fmaxf(fmaf(a[1], s16, b2v), 0.f) * w3v;
      p2 += fmaxf(fmaf(a[2], s16, b2v), 0.f) * w3v;
      p3 += fmaxf(fmaf(a[3], s16, b2v), 0.f) * w3v;
    }
#pragma unroll
    for (int m = 8; m >= 1; m >>= 1) {   // reduce over the 16 n-cols per quad
      p0 += __shfl_xor(p0, m, 16);
      p1 += __shfl_xor(p1, m, 16);
      p2 += __shfl_xor(p2, m, 16);
      p3 += __shfl_xor(p3, m, 16);
    }
    if (l15 == 0) {
      const int jl = jt * 32 + mt * 16 + quad * 4;   // global j of reg 0
      float ps[4] = {p0, p1, p2, p3};
#pragma unroll
      for (int r = 0; r < 4; ++r) {
        int j = jl + r;
        float sc = fast_tanh(ps[r] + b3v);
        bool valid = (j >= i + 2) && (j - i != 255);
        orow[mt * 16 + quad * 4 + r] = valid ? sc : 0.f;
      }
    }
  }
}

extern "C" void kernel_launch(void* const* d_in, const int* in_sizes, int n_in,
                              void* d_out, int out_size, void* d_ws, size_t ws_size,
                              hipStream_t stream) {
  const float* x  = (const float*)d_in[0];   // [8,256,128]
  const float* W1 = (const float*)d_in[1];   // [512,256]
  const float* b1 = (const float*)d_in[2];   // [256]
  const float* W2 = (const float*)d_in[3];   // [256,128]
  const float* b2 = (const float*)d_in[4];   // [128]
  const float* W3 = (const float*)d_in[5];   // [128]
  const float* b3 = (const float*)d_in[6];   // [1]
  float* out = (float*)d_out;

  // ws (ushort units): PiH 524288 | PjH 524288 | W1T 131072 | xcat 524288 | W2F8 32KB
  unsigned short* PiH  = (unsigned short*)d_ws;
  unsigned short* PjH  = PiH + 524288;
  unsigned short* W1T  = PjH + 524288;
  unsigned short* xcat = W1T + 131072;
  unsigned char*  W2F8 = (unsigned char*)(xcat + 524288);

  k_prep<<<4680, 256, 0, stream>>>(x, W1, W2, out, W2F8, W1T, xcat);
  k_proj<<<256, 256, 0, stream>>>(xcat, W1T, b1, PiH, PjH);
  k_main<<<2304, 256, 0, stream>>>(PiH, PjH, W2F8, b2, W3, b3, out + 2048);
}

// Round 8
// 94.215 us; speedup vs baseline: 1.0556x; 1.0324x over previous
//
#include <hip/hip_runtime.h>

// B=8, N=256, D=128, 2D=256.
// out = tour [8,256] (arange) ++ improvement_matrix [8,256,256].

typedef __attribute__((ext_vector_type(8))) short short8;
typedef __attribute__((ext_vector_type(8))) _Float16 half8;
typedef __attribute__((ext_vector_type(4))) float floatx4;

static __device__ __forceinline__ unsigned short f2bf(float f) {
  unsigned int x = __float_as_uint(f);
  x += 0x7fff + ((x >> 16) & 1);   // RNE fp32 -> bf16
  return (unsigned short)(x >> 16);
}

static __device__ __forceinline__ unsigned short f2h(float f) {
  _Float16 h = (_Float16)f;        // RNE fp32 -> fp16
  return __builtin_bit_cast(unsigned short, h);
}

static __device__ __forceinline__ float fast_tanh(float x) {
  float e = __expf(2.0f * fabsf(x));                       // e^{2|x|}
  float t = 1.0f - 2.0f * __builtin_amdgcn_rcpf(e + 1.0f); // in [0,1)
  return copysignf(t, x);
}

// pack 8 fp16 -> 8 OCP e4m3 bytes (via f32, v_cvt_pk_fp8_f32)
static __device__ __forceinline__ long pack_fp8(half8 s) {
  int lo = __builtin_amdgcn_cvt_pk_fp8_f32((float)s[0], (float)s[1], 0, false);
  lo = __builtin_amdgcn_cvt_pk_fp8_f32((float)s[2], (float)s[3], lo, true);
  int hi = __builtin_amdgcn_cvt_pk_fp8_f32((float)s[4], (float)s[5], 0, false);
  hi = __builtin_amdgcn_cvt_pk_fp8_f32((float)s[6], (float)s[7], hi, true);
  return (long)(unsigned)lo | ((long)hi << 32);
}

// async global->LDS DMA, 16B per lane. LDS dest = wave-uniform base + lane*16
// (m104); global src is per-lane. Swizzled layouts are achieved by
// PRE-SWIZZLING the global buffer (m173 pattern), dest stays linear.
static __device__ __forceinline__ void gload_lds16(const void* g, void* l) {
  __builtin_amdgcn_global_load_lds(
      (const __attribute__((address_space(1))) unsigned int*)g,
      (__attribute__((address_space(3))) unsigned int*)l, 16, 0, 0);
}

// ---- k_prep: W1 -> bf16 transpose ONLY (512 blocks). -----------------------
// R8: xcat is GONE (each row had exactly one consumer -> k_proj now builds
// its As tile in-block from x). out-fill + W2F8 moved to k_proj extra blocks.
// W1T [512 n][256 k], chunk-swizzled: v=k>>3, sw=(((v&16)|((v^(n&15))&15))<<3)|(k&7).
__global__ __launch_bounds__(256) void k_prep(
    const float* __restrict__ W1, unsigned short* __restrict__ W1T) {
  int e = blockIdx.x * 256 + threadIdx.x;   // 131072
  int n = e >> 8, k = e & 255;
  int v = k >> 3;
  int sw = (((v & 16) | ((v ^ (n & 15)) & 15)) << 3) | (k & 7);
  W1T[(n << 8) + sw] = f2bf(W1[((k + (n & 256)) << 8) + (n & 255)]);
}

// ---- k_proj: blocks 0-255 GEMM; 256-769 out-fill; 770-833 W2F8. ------------
// GEMM [2048 rows x 256 K] @ [K x 512 ch] -> PiH | PjH.
//   As tile now built IN-BLOCK from x (coalesced float4 + f2bf + swizzled
//   ds_write_b128; LDS bytes identical to the old xcat-DMA path).
//   Bs staged via global_load_lds from pre-swizzled W1T.
// PiH LINEAR; PjH chunk-swizzled per row (key row&15): c=chan>>3 ->
//   c'=(c&16)|((c^(row&15))&15), so k_main DMAs the jt tile linearly.
// W2F8 layout (paired for b128 B-frag reads): chan n -> q=n>>5, which=(n>>4)&1,
//   l=n&15; k-chunk c=k>>3, c'=(c&16)|((c^l)&15);
//   byte = q*8192 + l*512 + c'*16 + which*8 + (k&7).
__global__ __launch_bounds__(256) void k_proj(
    const float* __restrict__ x, const unsigned short* __restrict__ W1T,
    const float* __restrict__ b1, unsigned short* __restrict__ PiH,
    unsigned short* __restrict__ PjH, const float* __restrict__ W2,
    float* __restrict__ out, unsigned char* __restrict__ W2F8) {
  const int tid = threadIdx.x;
  const int bx = blockIdx.x;

  if (bx >= 256) {
    if (bx < 770) {                        // ---- out-fill, float4 ----
      int t = (bx - 256) * 256 + tid;      // 0..131583
      int e = t * 4;                       // covers 526336 floats exactly
      floatx4 w;
      if (e < 2048) {
        float v = (float)(e & 255);        // e%4==0 -> (e&255)+i stays <256
        w = (floatx4){v, v + 1.f, v + 2.f, v + 3.f};
      } else {
        w = (floatx4)0.f;
      }
      *(floatx4*)(out + e) = w;
    } else {                               // ---- W2 -> fp8(x16) paired ----
      int t = (bx - 770) * 256 + tid;      // 16384 k-pairs
      int p = t >> 7, n = t & 127;         // p = k/2, n = out channel
      float f0 = W2[(2 * p) * 128 + n] * 16.f;   // x16: e4m3 normal range
      float f1 = W2[(2 * p + 1) * 128 + n] * 16.f;
      int v2 = __builtin_amdgcn_cvt_pk_fp8_f32(f0, f1, 0, false);
      int q = n >> 5, which = (n >> 4) & 1, l = n & 15;
      int c = p >> 2, off = (p & 3) * 2;   // k-chunk = k>>3 = p>>2
      int cs = (c & 16) | ((c ^ l) & 15);
      *(unsigned short*)(W2F8 + q * 8192 + l * 512 + cs * 16 + which * 8 + off) =
          (unsigned short)(v2 & 0xffff);
    }
    return;
  }

  const int mg = bx >> 3;               // 0..31 row-tile
  const int ng = bx & 7;                // 0..7 channel-tile
  const int wr = tid >> 6, lane = tid & 63, quad = lane >> 4, l15 = lane & 15;

  __shared__ unsigned short As[64 * 256];   // 32KB rows tile (swizzled)
  __shared__ unsigned short Bs[64 * 256];   // 32KB W1T tile (swizzled)

  // Bs: DMA from pre-swizzled W1T (linear dest)
  const unsigned short* Bsrc = W1T + ng * 64 * 256;
#pragma unroll
  for (int it = 0; it < 8; ++it) {
    const int c = it * 256 + wr * 64 + lane;     // 16B chunk id 0..2047
    gload_lds16(Bsrc + c * 8, &Bs[(it * 256 + wr * 64) * 8]);
  }

  // As: build in-block from x. 8 passes; tid -> (row8 = tid>>5, v = tid&31).
  // Row r chunk v covers k=v*8..+7: v<16 -> x[b][pos][..], v>=16 -> pos+1.
  // Write at swizzled chunk slot -> LDS bytes identical to old xcat path.
#pragma unroll
  for (int pass = 0; pass < 8; ++pass) {
    const int rr = pass * 8 + (tid >> 5);        // tile row 0..63
    const int grow = mg * 64 + rr;               // global row = b*256+pos
    const int pos = grow & 255, bb = grow >> 8;
    const int v = tid & 31;
    const int pos2 = (v < 16) ? pos : ((pos + 1) & 255);
    const float* src = x + (bb * 256 + pos2) * 128 + (v & 15) * 8;
    const floatx4 f0 = *(const floatx4*)(src);
    const floatx4 f1 = *(const floatx4*)(src + 4);
    union { short8 s; unsigned short u[8]; } o;
    o.u[0] = f2bf(f0[0]); o.u[1] = f2bf(f0[1]);
    o.u[2] = f2bf(f0[2]); o.u[3] = f2bf(f0[3]);
    o.u[4] = f2bf(f1[0]); o.u[5] = f2bf(f1[1]);
    o.u[6] = f2bf(f1[2]); o.u[7] = f2bf(f1[3]);
    const int sw = (v & 16) | ((v ^ (rr & 15)) & 15);
    *(short8*)((char*)As + rr * 512 + sw * 16) = o.s;
  }
  __syncthreads();   // drains ds_writes (lgkm) + DMA (vmcnt)

  floatx4 acc[4];
#pragma unroll
  for (int mt = 0; mt < 4; ++mt) acc[mt] = (floatx4)0.f;

  const char* Ab = (const char*)As;
  const char* Bb = (const char*)Bs + wr * 16 * 512;
  const int base_sw = l15 * 512 + ((quad ^ l15) << 4);

#pragma unroll
  for (int ks = 0; ks < 8; ++ks) {
    const int swz = base_sw ^ (ks << 6);
    short8 bfr = *(const short8*)(Bb + swz);
#pragma unroll
    for (int mt = 0; mt < 4; ++mt) {
      short8 afr = *(const short8*)(Ab + mt * 8192 + swz);
      acc[mt] = __builtin_amdgcn_mfma_f32_16x16x32_bf16(afr, bfr, acc[mt], 0, 0, 0);
    }
  }

  const int ch = ng * 64 + wr * 16 + l15;          // 0..511 (wave-uniform side)
  const float bias = (ch < 256) ? b1[ch] : 0.f;
  const bool isPi = (ch < 256);
  unsigned short* dst = isPi ? PiH : PjH;
  const int chan = ch & 255;
  const int ck = chan >> 3, coff = chan & 7;
#pragma unroll
  for (int mt = 0; mt < 4; ++mt)
#pragma unroll
    for (int r = 0; r < 4; ++r) {
      int row = mg * 64 + mt * 16 + quad * 4 + r;  // global row b*256+pos
      int cpos;
      if (isPi) cpos = chan;
      else {
        int cs = (ck & 16) | ((ck ^ (row & 15)) & 15);
        cpos = cs * 8 + coff;
      }
      dst[row * 256 + cpos] = f2h(acc[mt][r] + bias);
    }
}

// ---- k_main: R7 verbatim (build-ahead pipeline; 97.27us, clean). -----------
__global__ __launch_bounds__(256, 3) void k_main(
    const unsigned short* __restrict__ PiH, const unsigned short* __restrict__ PjH,
    const unsigned char* __restrict__ W2F8, const float* __restrict__ b2,
    const float* __restrict__ W3, const float* __restrict__ b3,
    float* __restrict__ outm) {
  const int tid = threadIdx.x;
  const int wr = tid >> 6;              // wave 0..3
  const int lane = tid & 63, quad = lane >> 4, l15 = lane & 15;

  __shared__ unsigned char W2s[32768];  // paired+swizzled fp8
  __shared__ unsigned char PjS[16384];  // 32 rows x 512B, chunk-swizzled
  __shared__ unsigned char PiS[4096];   // 4 waves x 1024B (row duplicated)

  // decode block -> (b, jt, i-base)   [block-uniform except wr]
  const int bid = blockIdx.x;
  const int b = bid / 288;
  const int rem = bid - b * 288;
  int jt = 0, basej = 0;
  if (rem >= 8)   { jt = 1; basej = 8;   }
  if (rem >= 24)  { jt = 2; basej = 24;  }
  if (rem >= 48)  { jt = 3; basej = 48;  }
  if (rem >= 80)  { jt = 4; basej = 80;  }
  if (rem >= 120) { jt = 5; basej = 120; }
  if (rem >= 168) { jt = 6; basej = 168; }
  if (rem >= 224) { jt = 7; basej = 224; }
  const int i = (rem - basej) * 4 + wr;      // 0 .. (jt+1)*32-1 (2 pads/group)

  // stage W2 32KB (2048 chunks) + Pj tile 16KB (1024 chunks) + Pi row/wave
  const unsigned char* pjsrc =
      (const unsigned char*)(PjH + ((b << 8) + jt * 32) * 256);
  const unsigned char* pisrc =
      (const unsigned char*)(PiH + ((b << 8) + i) * 256);
#pragma unroll
  for (int it = 0; it < 8; ++it) {
    const int c = it * 256 + wr * 64 + lane;
    gload_lds16(W2F8 + c * 16, &W2s[(it * 256 + wr * 64) * 16]);
  }
#pragma unroll
  for (int it = 0; it < 4; ++it) {
    const int c = it * 256 + wr * 64 + lane;
    gload_lds16(pjsrc + c * 16, &PjS[(it * 256 + wr * 64) * 16]);
  }
  gload_lds16(pisrc + (lane & 31) * 16, &PiS[wr * 1024]);  // dup in hi 512B
  __syncthreads();

  const char* W2base = (const char*)&W2s[0];
  const char* PjBase = (const char*)&PjS[0];
  const char* PiBase = (const char*)&PiS[0] + wr * 1024 + quad * 16;
  // shared chunk-swizzle base for W2 and Pj ([16 rows x 512B], c = ks*4+quad):
  const int sw16 = l15 * 512 + (((quad ^ l15) & 15) << 4);

  floatx4 acc[2][8];
#pragma unroll
  for (int mt = 0; mt < 2; ++mt)
#pragma unroll
    for (int nt = 0; nt < 8; ++nt) acc[mt][nt] = (floatx4)0.f;

  union U4 { uint4 v; half8 h; };
  U4 piR[2], pjR[2][2];                 // depth-2 ring, parity-indexed
  piR[0].v = *(const uint4*)(PiBase);
  pjR[0][0].v = *(const uint4*)(PjBase + sw16);
  pjR[0][1].v = *(const uint4*)(PjBase + 8192 + sw16);   // mt=1: +16 rows
  piR[1].v = *(const uint4*)(PiBase + 64);               // ks=1 operands
  {
    const char* pj = PjBase + (sw16 ^ 64);
    pjR[1][0].v = *(const uint4*)(pj);
    pjR[1][1].v = *(const uint4*)(pj + 8192);
  }

  uint4 bfA[4], bfB[4];
  {
    const char* b0 = W2base + sw16;
#pragma unroll
    for (int q = 0; q < 4; ++q) bfA[q] = *(const uint4*)(b0 + q * 8192);
  }

  // build A(0) in the prologue; loop builds A(ks+1) ahead of burst(ks)
  long aC0, aC1;
  {
    const half8 s0 = __builtin_elementwise_max(piR[0].h + pjR[0][0].h,
                                               (half8)(_Float16)0);
    const half8 s1 = __builtin_elementwise_max(piR[0].h + pjR[0][1].h,
                                               (half8)(_Float16)0);
    aC0 = pack_fp8(s0);
    aC1 = pack_fp8(s1);
  }

#pragma unroll
  for (int ks = 0; ks < 8; ++ks) {
    // (1) issue NEXT iteration's B-frag reads (4x b128, paired chans)
    if (ks < 7) {
      const char* bn = W2base + (sw16 ^ ((ks + 1) << 6));
#pragma unroll
      for (int q = 0; q < 4; ++q)
        ((ks & 1) ? bfA : bfB)[q] = *(const uint4*)(bn + q * 8192);
    }
    // (2) depth-2 LDS prefetch of pi/pj for ks+2 (into parity slot ks&1)
    if (ks < 6) {
      piR[ks & 1].v = *(const uint4*)(PiBase + (ks + 2) * 64);
      const char* pj = PjBase + (sw16 ^ ((ks + 2) << 6));
      pjR[ks & 1][0].v = *(const uint4*)(pj);
      pjR[ks & 1][1].v = *(const uint4*)(pj + 8192);
    }
    // (3) BUILD-AHEAD: A(ks+1) from piR[(ks+1)&1] (loaded >=1 iter ago)
    long aN0 = 0, aN1 = 0;
    if (ks < 7) {
      const half8 s0 = __builtin_elementwise_max(
          piR[(ks + 1) & 1].h + pjR[(ks + 1) & 1][0].h, (half8)(_Float16)0);
      const half8 s1 = __builtin_elementwise_max(
          piR[(ks + 1) & 1].h + pjR[(ks + 1) & 1][1].h, (half8)(_Float16)0);
      aN0 = pack_fp8(s0);
      aN1 = pack_fp8(s1);
    }
    // (4) MFMA burst ks with A built LAST iteration (no dep on step 3)
    const uint4* bc = (ks & 1) ? bfB : bfA;
    __builtin_amdgcn_s_setprio(1);
#pragma unroll
    for (int q = 0; q < 4; ++q) {
      const long blo = (long)bc[q].x | ((long)bc[q].y << 32);
      const long bhi = (long)bc[q].z | ((long)bc[q].w << 32);
      acc[0][2 * q]     = __builtin_amdgcn_mfma_f32_16x16x32_fp8_fp8(aC0, blo, acc[0][2 * q], 0, 0, 0);
      acc[1][2 * q]     = __builtin_amdgcn_mfma_f32_16x16x32_fp8_fp8(aC1, blo, acc[1][2 * q], 0, 0, 0);
      acc[0][2 * q + 1] = __builtin_amdgcn_mfma_f32_16x16x32_fp8_fp8(aC0, bhi, acc[0][2 * q + 1], 0, 0, 0);
      acc[1][2 * q + 1] = __builtin_amdgcn_mfma_f32_16x16x32_fp8_fp8(aC1, bhi, acc[1][2 * q + 1], 0, 0, 0);
    }
    __builtin_amdgcn_s_setprio(0);
    if (ks < 7) { aC0 = aN0; aC1 = aN1; }
  }

  // epilogue: score[j] = tanh(sum_n W3[n]*relu(C[j,n]/16 + b2[n]) + b3)
  float* orow = outm + ((b << 8) + i) * 256 + jt * 32;
  const float b3v = b3[0];
  const float s16 = 0.0625f;               // undo W2 x16 scale
#pragma unroll
  for (int mt = 0; mt < 2; ++mt) {
    float p0 = 0, p1 = 0, p2 = 0, p3 = 0;
#pragma unroll
    for (int nt = 0; nt < 8; ++nt) {
      float w3v = W3[nt * 16 + l15];
      float b2v = b2[nt * 16 + l15];
      floatx4 a = acc[mt][nt];
      p0 += fmaxf(fmaf(a[0], s16, b2v), 0.f) * w3v;
      p1 += fmaxf(fmaf(a[1], s16, b2v), 0.f) * w3v;
      p2 += fmaxf(fmaf(a[2], s16, b2v), 0.f) * w3v;
      p3 += fmaxf(fmaf(a[3], s16, b2v), 0.f) * w3v;
    }
#pragma unroll
    for (int m = 8; m >= 1; m >>= 1) {   // reduce over the 16 n-cols per quad
      p0 += __shfl_xor(p0, m, 16);
      p1 += __shfl_xor(p1, m, 16);
      p2 += __shfl_xor(p2, m, 16);
      p3 += __shfl_xor(p3, m, 16);
    }
    if (l15 == 0) {
      const int jl = jt * 32 + mt * 16 + quad * 4;   // global j of reg 0
      float ps[4] = {p0, p1, p2, p3};
#pragma unroll
      for (int r = 0; r < 4; ++r) {
        int j = jl + r;
        float sc = fast_tanh(ps[r] + b3v);
        bool valid = (j >= i + 2) && (j - i != 255);
        orow[mt * 16 + quad * 4 + r] = valid ? sc : 0.f;
      }
    }
  }
}

extern "C" void kernel_launch(void* const* d_in, const int* in_sizes, int n_in,
                              void* d_out, int out_size, void* d_ws, size_t ws_size,
                              hipStream_t stream) {
  const float* x  = (const float*)d_in[0];   // [8,256,128]
  const float* W1 = (const float*)d_in[1];   // [512,256]
  const float* b1 = (const float*)d_in[2];   // [256]
  const float* W2 = (const float*)d_in[3];   // [256,128]
  const float* b2 = (const float*)d_in[4];   // [128]
  const float* W3 = (const float*)d_in[5];   // [128]
  const float* b3 = (const float*)d_in[6];   // [1]
  float* out = (float*)d_out;

  // ws (ushort units): PiH 524288 | PjH 524288 | W1T 131072 | W2F8 32KB
  unsigned short* PiH  = (unsigned short*)d_ws;
  unsigned short* PjH  = PiH + 524288;
  unsigned short* W1T  = PjH + 524288;
  unsigned char*  W2F8 = (unsigned char*)(W1T + 131072);

  k_prep<<<512, 256, 0, stream>>>(W1, W1T);
  k_proj<<<834, 256, 0, stream>>>(x, W1T, b1, PiH, PjH, W2, out, W2F8);
  k_main<<<2304, 256, 0, stream>>>(PiH, PjH, W2F8, b2, W3, b3, out + 2048);
}